// Round 3
// baseline (177.053 us; speedup 1.0000x reference)
//
#include <hip/hip_runtime.h>
#include <hip/hip_bf16.h>
#include <math.h>

#define B_ 16
#define C_ 64
#define N_ 4096   // 64*64 pixels
#define M_ 1024   // 32*32 pooled keys

typedef __attribute__((ext_vector_type(8))) short v8s;   // 8 bf16 (4 VGPRs)
typedef __attribute__((ext_vector_type(4))) float v4f;   // 4 fp32 acc

__device__ inline unsigned short f2bf(float f) {
    __hip_bfloat16 h = __float2bfloat16(f);
    return *(unsigned short*)&h;
}
__device__ inline unsigned pack2bf(float a, float b) {
    return (unsigned)f2bf(a) | ((unsigned)f2bf(b) << 16);
}

// ---------------------------------------------------------------------------
// Kernel 1: fused 1x1 convs + 2x2 maxpool. One thread per pixel. Input
// channels processed in 4 passes of 16 (pass loop FORCED ROLLED so the
// compiler cannot hoist all 64 x-loads and fall back to re-loading x per
// output row — the round-2 disease: VGPR=72 proved x was not resident).
// Live set: 16 xv + 48 acc ~ 85 VGPR. Weights are wave-uniform contiguous
// -> scalar s_load pipe.
// Outputs bf16: thetaT [b][n][8], phiT [b][m][8], gcm [b][c(32)][m(1024)].
// ---------------------------------------------------------------------------
__global__ __launch_bounds__(256) void conv_pool_k(
    const float* __restrict__ x,
    const float* __restrict__ Wt, const float* __restrict__ bt,
    const float* __restrict__ Wp, const float* __restrict__ bp,
    const float* __restrict__ Wg, const float* __restrict__ bg,
    unsigned short* __restrict__ thetaT,
    unsigned short* __restrict__ phiT,
    unsigned short* __restrict__ gcm)
{
    const int tid = threadIdx.x;
    const int bx  = blockIdx.x;
    const int b   = bx >> 4;
    const int py0 = (bx & 15) << 2;   // 4 image rows per block

    const int q   = tid >> 2, sub = tid & 3;   // quad id, position in 2x2
    const int prl = q >> 5,   pc  = q & 31;    // local pooled row, pooled col
    const int py  = py0 + prl * 2 + (sub >> 1);
    const int px  = pc * 2 + (sub & 1);
    const int n   = py * 64 + px;

    const float* xp = x + (size_t)b * C_ * N_ + n;

    float at[8], ap[8], ag[32];
    #pragma unroll
    for (int o = 0; o < 8; ++o) { at[o] = bt[o]; ap[o] = bp[o]; }
    #pragma unroll
    for (int o = 0; o < 32; ++o) ag[o] = bg[o];

    float xv[16];
    #pragma unroll 1
    for (int pass = 0; pass < 4; ++pass) {
        const int c0 = pass * 16;
        #pragma unroll
        for (int j = 0; j < 16; ++j) xv[j] = xp[(size_t)(c0 + j) * N_];
        #pragma unroll
        for (int j = 0; j < 16; ++j) {
            const float xj = xv[j];
            const int c = c0 + j;
            #pragma unroll
            for (int o = 0; o < 8; ++o)  at[o] = fmaf(xj, Wt[o * 64 + c], at[o]);
            #pragma unroll
            for (int o = 0; o < 8; ++o)  ap[o] = fmaf(xj, Wp[o * 64 + c], ap[o]);
            #pragma unroll
            for (int o = 0; o < 32; ++o) ag[o] = fmaf(xj, Wg[o * 64 + c], ag[o]);
        }
    }

    // theta: bf16, [n][8] contiguous (16B per pixel)
    {
        unsigned u[4];
        #pragma unroll
        for (int j = 0; j < 4; ++j) u[j] = pack2bf(at[2*j], at[2*j+1]);
        uint4* tp = (uint4*)(thetaT + ((size_t)b * N_ + n) * 8);
        *tp = make_uint4(u[0], u[1], u[2], u[3]);
    }

    // 2x2 maxpool across the quad
    #pragma unroll
    for (int o = 0; o < 8; ++o) {
        float v = ap[o];
        v = fmaxf(v, __shfl_xor(v, 1));
        v = fmaxf(v, __shfl_xor(v, 2));
        ap[o] = v;
    }
    #pragma unroll
    for (int o = 0; o < 32; ++o) {
        float v = ag[o];
        v = fmaxf(v, __shfl_xor(v, 1));
        v = fmaxf(v, __shfl_xor(v, 2));
        ag[o] = v;
    }

    if (sub == 0) {
        const int m = ((py0 >> 1) + prl) * 32 + pc;   // pooled index [0,1024)
        unsigned u[4];
        #pragma unroll
        for (int j = 0; j < 4; ++j) u[j] = pack2bf(ap[2*j], ap[2*j+1]);
        uint4* pp = (uint4*)(phiT + ((size_t)b * M_ + m) * 8);
        *pp = make_uint4(u[0], u[1], u[2], u[3]);
        #pragma unroll
        for (int c = 0; c < 32; ++c)
            gcm[((size_t)(b * 32 + c)) * M_ + m] = f2bf(ag[c]);
    }
}

// ---------------------------------------------------------------------------
// Kernel 2: MFMA flash attention + fused output conv + residual.
// (unchanged from round 2 — passed with absmax 0.0156)
// Block: 256 thr = 4 waves; wave owns 32 queries (2 x 16); block = 128 q.
// Grid: 16 b x 32 = 512 blocks.
// Layouts (measured, m89/m91/m120):
//   A[m][k]: m = lane&15, k = (lane>>4)*8 + j
//   B[k][n]: n = lane&15, k = (lane>>4)*8 + j
//   C/D   : col = lane&15, row = (lane>>4)*4 + reg
// ---------------------------------------------------------------------------
#define GPAD   264   // sgT row stride (shorts): 256 + 8 -> 2-way banks (free)
#define PROW   40    // sP row stride (shorts): 80 B, 16B-aligned

__global__ __launch_bounds__(256) void attn_k(
    const float* __restrict__ x,
    const unsigned short* __restrict__ thetaT,
    const unsigned short* __restrict__ phiT,
    const unsigned short* __restrict__ gcm,
    const float* __restrict__ Wo, const float* __restrict__ bo,
    const float* __restrict__ gammap,
    float* __restrict__ out)
{
    __shared__ unsigned short sphi[2][128][8];   // 4 KB  even/odd key split
    __shared__ unsigned short sgT[32][GPAD];     // 16.9 KB [c][m]
    __shared__ unsigned short sP[4][32][PROW];   // 10.25 KB per-wave P slabs
    __shared__ float sO[32][132];                // 16.9 KB [c][q] epilogue

    const int tid  = threadIdx.x;
    const int lane = tid & 63;
    const int wid  = tid >> 6;
    const int l15  = lane & 15;
    const int l4   = lane >> 4;

    const int b  = blockIdx.x >> 5;
    const int q0 = (blockIdx.x & 31) << 7;   // 128 queries per block
    const int qw = q0 + wid * 32;            // this wave's first query

    // theta A-fragments (K=8 real, rest zero): lanes 16..63 are zero
    v8s aT[2];
    {
        v8s z = {};
        aT[0] = z; aT[1] = z;
        if (l4 == 0) {
            aT[0] = *(const v8s*)(thetaT + ((size_t)b * N_ + qw +      l15) * 8);
            aT[1] = *(const v8s*)(thetaT + ((size_t)b * N_ + qw + 16 + l15) * 8);
        }
    }

    v4f accO[2][2];
    #pragma unroll
    for (int qs = 0; qs < 2; ++qs)
        #pragma unroll
        for (int ct = 0; ct < 2; ++ct) { v4f z = {}; accO[qs][ct] = z; }
    float lsum[2][4] = {{0.f,0.f,0.f,0.f},{0.f,0.f,0.f,0.f}};
    const v4f zf = {};

    for (int t = 0; t < 4; ++t) {            // 4 key tiles of 256
        __syncthreads();
        // stage phi tile, split even/odd keys
        {
            const uint4 v = *(const uint4*)(phiT + ((size_t)b * M_ + t * 256 + tid) * 8);
            *(uint4*)&sphi[tid & 1][tid >> 1][0] = v;
        }
        // stage g tile channel-major [c][m]
        {
            const int row = tid >> 3, ch = tid & 7;
            const uint4* src = (const uint4*)(gcm + ((size_t)(b * 32 + row)) * M_ + t * 256 + ch * 32);
            uint4* dst = (uint4*)&sgT[row][ch * 32];
            dst[0] = src[0]; dst[1] = src[1]; dst[2] = src[2]; dst[3] = src[3];
        }
        __syncthreads();

        for (int cc = 0; cc < 8; ++cc) {     // 32-key chunks
            // phi B-frags: subtile kt covers keys {cc*32 + 2n + kt}
            v8s bph0, bph1;
            { v8s z = {}; bph0 = z; bph1 = z; }
            if (l4 == 0) {
                bph0 = *(const v8s*)&sphi[0][cc * 16 + l15][0];
                bph1 = *(const v8s*)&sphi[1][cc * 16 + l15][0];
            }
            // S tiles + exp + pack into per-wave sP slab (natural key order)
            #pragma unroll
            for (int qs = 0; qs < 2; ++qs) {
                v4f s0 = __builtin_amdgcn_mfma_f32_16x16x32_bf16(aT[qs], bph0, zf, 0, 0, 0);
                v4f s1 = __builtin_amdgcn_mfma_f32_16x16x32_bf16(aT[qs], bph1, zf, 0, 0, 0);
                #pragma unroll
                for (int r = 0; r < 4; ++r) {
                    float e0 = __expf(s0[r]);   // key cc*32 + 2*l15
                    float e1 = __expf(s1[r]);   // key cc*32 + 2*l15 + 1
                    lsum[qs][r] += e0 + e1;
                    *(unsigned*)&sP[wid][qs * 16 + l4 * 4 + r][2 * l15] = pack2bf(e0, e1);
                }
            }
            // G B-frags (shared by both q-subtiles)
            v8s bg0 = *(const v8s*)&sgT[l15     ][cc * 32 + l4 * 8];
            v8s bg1 = *(const v8s*)&sgT[16 + l15][cc * 32 + l4 * 8];
            // P A-frags (round-trip) + O MFMAs
            #pragma unroll
            for (int qs = 0; qs < 2; ++qs) {
                v8s ap = *(const v8s*)&sP[wid][qs * 16 + l15][l4 * 8];
                accO[qs][0] = __builtin_amdgcn_mfma_f32_16x16x32_bf16(ap, bg0, accO[qs][0], 0, 0, 0);
                accO[qs][1] = __builtin_amdgcn_mfma_f32_16x16x32_bf16(ap, bg1, accO[qs][1], 0, 0, 0);
            }
        }
    }

    // softmax denominators: reduce across the 16 key-columns (lane&15 groups)
    float rl[2][4];
    #pragma unroll
    for (int qs = 0; qs < 2; ++qs)
        #pragma unroll
        for (int r = 0; r < 4; ++r) {
            float v = lsum[qs][r];
            v += __shfl_xor(v, 1);
            v += __shfl_xor(v, 2);
            v += __shfl_xor(v, 4);
            v += __shfl_xor(v, 8);
            rl[qs][r] = 1.0f / v;
        }

    // write normalized O to LDS [c][q]
    #pragma unroll
    for (int qs = 0; qs < 2; ++qs)
        #pragma unroll
        for (int ct = 0; ct < 2; ++ct)
            #pragma unroll
            for (int r = 0; r < 4; ++r)
                sO[ct * 16 + l15][wid * 32 + qs * 16 + l4 * 4 + r] =
                    accO[qs][ct][r] * rl[qs][r];
    __syncthreads();

    // epilogue: out = gamma*(Wo . O + bo) + x.  Wave-uniform oc set ->
    // Wo/bo via scalar loads; O column from LDS (conflict-free).
    {
        const int qq   = tid & 127;
        const int half = tid >> 7;          // 0: oc 0..31, 1: oc 32..63
        const int n    = q0 + qq;
        float col[32];
        #pragma unroll
        for (int c = 0; c < 32; ++c) col[c] = sO[c][qq];
        const float gamma = *gammap;
        const float* xb = x   + ((size_t)(b * 64 + half * 32)) * N_ + n;
        float*       ob = out + ((size_t)(b * 64 + half * 32)) * N_ + n;
        #pragma unroll
        for (int j = 0; j < 32; ++j) {
            const int oc = half * 32 + j;
            const float* w = Wo + oc * 32;   // uniform -> s_load
            float r = 0.f;
            #pragma unroll
            for (int c = 0; c < 32; ++c) r = fmaf(w[c], col[c], r);
            ob[(size_t)j * N_] = gamma * (r + bo[oc]) + xb[(size_t)j * N_];
        }
    }
}

// ---------------------------------------------------------------------------
extern "C" void kernel_launch(void* const* d_in, const int* in_sizes, int n_in,
                              void* d_out, int out_size, void* d_ws, size_t ws_size,
                              hipStream_t stream) {
    const float* x  = (const float*)d_in[0];
    const float* Wt = (const float*)d_in[1];
    const float* bt = (const float*)d_in[2];
    const float* Wp = (const float*)d_in[3];
    const float* bp = (const float*)d_in[4];
    const float* Wg = (const float*)d_in[5];
    const float* bg = (const float*)d_in[6];
    const float* Wo = (const float*)d_in[7];
    const float* bo = (const float*)d_in[8];
    const float* gm = (const float*)d_in[9];
    float* out = (float*)d_out;

    // workspace (bf16): thetaT [16][4096][8] | phiT [16][1024][8] | gcm [16][32][1024]
    unsigned short* thetaT = (unsigned short*)d_ws;
    unsigned short* phiT   = thetaT + (size_t)B_ * N_ * 8;
    unsigned short* gcm    = phiT   + (size_t)B_ * M_ * 8;

    hipLaunchKernelGGL(conv_pool_k, dim3(256), dim3(256), 0, stream,
                       x, Wt, bt, Wp, bp, Wg, bg, thetaT, phiT, gcm);
    hipLaunchKernelGGL(attn_k, dim3(512), dim3(256), 0, stream,
                       x, thetaT, phiT, gcm, Wo, bo, gm, out);
}

// Round 4
// 120.981 us; speedup vs baseline: 1.4635x; 1.4635x over previous
//
#include <hip/hip_runtime.h>
#include <hip/hip_bf16.h>
#include <math.h>

#define B_ 16
#define C_ 64
#define N_ 4096   // 64*64 pixels
#define M_ 1024   // 32*32 pooled keys

typedef __attribute__((ext_vector_type(8))) short v8s;   // 8 bf16 (4 VGPRs)
typedef __attribute__((ext_vector_type(4))) float v4f;   // 4 fp32 acc

__device__ inline unsigned short f2bf(float f) {
    __hip_bfloat16 h = __float2bfloat16(f);
    return *(unsigned short*)&h;
}
__device__ inline unsigned pack2bf(float a, float b) {
    return (unsigned)f2bf(a) | ((unsigned)f2bf(b) << 16);
}
__device__ inline v8s cvt8(float4 a, float4 b) {
    union { v8s v; unsigned u[4]; } r;
    r.u[0] = pack2bf(a.x, a.y);
    r.u[1] = pack2bf(a.z, a.w);
    r.u[2] = pack2bf(b.x, b.y);
    r.u[3] = pack2bf(b.z, b.w);
    return r.v;
}

// ---------------------------------------------------------------------------
// Kernel 1 (round 4): MFMA conv. D[48][n] = W[48][64] . x[64][n] as a GEMM:
// weights live in A-fragments (24 VGPRs, loaded ONCE — kills the round-2/3
// disease of streaming 12 KB of weights past every thread every iteration).
// Wave = one image row (64 px, 4 n-tiles of 16); block = 4 waves = 4 rows;
// grid = 16 batches x 16 row-groups. B-frags: lane (l15,l4) loads 8
// channel-strided fp32 of pixel l15 (coalesced 64B segments), packs to bf16.
// m-tiles: 0 = [theta(8); phi(8)], 1 = g[0..15], 2 = g[16..31].
// Epilogue: theta written from C-regs; phi/g staged fp32 in LDS, 2x2
// max-pooled, stored in attn layouts (phiT [m][8], gcm [c][m]).
// MFMA layouts (measured m89/m91): A[m=l15][k=l4*8+j], B[k=l4*8+j][n=l15],
// C/D: col(n)=l15, row(m)=l4*4+reg.
// ---------------------------------------------------------------------------
#define SPSTR 268   // sPool row stride (floats): 268%32=12 -> 2-way banks

__global__ __launch_bounds__(256) void conv_pool_k(
    const float* __restrict__ x,
    const float* __restrict__ Wt, const float* __restrict__ bt,
    const float* __restrict__ Wp, const float* __restrict__ bp,
    const float* __restrict__ Wg, const float* __restrict__ bg,
    unsigned short* __restrict__ thetaT,
    unsigned short* __restrict__ phiT,
    unsigned short* __restrict__ gcm)
{
    __shared__ float sPool[40 * SPSTR];   // 42.9 KB: ch 0..7 = phi, 8..39 = g

    const int tid  = threadIdx.x;
    const int lane = tid & 63;
    const int wid  = tid >> 6;
    const int l15  = lane & 15;
    const int l4   = lane >> 4;

    const int b  = blockIdx.x >> 4;
    const int y0 = (blockIdx.x & 15) << 2;   // first of 4 image rows
    const int y  = y0 + wid;                 // this wave's row

    // --- A-fragments: weights, 3 m-tiles x 2 k-halves (bf16, loaded once)
    const float* row0 = (l15 < 8) ? (Wt + l15 * 64) : (Wp + (l15 - 8) * 64);
    const float* row1 = Wg + l15 * 64;
    const float* row2 = Wg + (16 + l15) * 64;
    v8s afrag[3][2];
    #pragma unroll
    for (int kh = 0; kh < 2; ++kh) {
        const int c0 = kh * 32 + l4 * 8;
        afrag[0][kh] = cvt8(*(const float4*)(row0 + c0), *(const float4*)(row0 + c0 + 4));
        afrag[1][kh] = cvt8(*(const float4*)(row1 + c0), *(const float4*)(row1 + c0 + 4));
        afrag[2][kh] = cvt8(*(const float4*)(row2 + c0), *(const float4*)(row2 + c0 + 4));
    }

    // --- accumulators init = bias (C-layout: row o = l4*4+r)
    v4f acc[4][3];
    {
        float bv[3][4];
        #pragma unroll
        for (int r = 0; r < 4; ++r) {
            const int o = l4 * 4 + r;               // 0..15
            bv[0][r] = (o < 8) ? bt[o] : bp[o - 8];
            bv[1][r] = bg[o];
            bv[2][r] = bg[16 + o];
        }
        #pragma unroll
        for (int nt = 0; nt < 4; ++nt)
            #pragma unroll
            for (int t = 0; t < 3; ++t) {
                v4f a; a[0] = bv[t][0]; a[1] = bv[t][1];
                a[2] = bv[t][2]; a[3] = bv[t][3];
                acc[nt][t] = a;
            }
    }

    // --- main GEMM: 4 n-tiles x 2 k-halves x 3 m-tiles
    const float* xb = x + (size_t)b * C_ * N_ + y * 64;
    #pragma unroll
    for (int nt = 0; nt < 4; ++nt) {
        const int n0 = nt * 16 + l15;
        #pragma unroll
        for (int kh = 0; kh < 2; ++kh) {
            const int cb = kh * 32 + l4 * 8;
            float f[8];
            #pragma unroll
            for (int j = 0; j < 8; ++j) f[j] = xb[(size_t)(cb + j) * N_ + n0];
            union { v8s v; unsigned u[4]; } bf;
            #pragma unroll
            for (int j = 0; j < 4; ++j) bf.u[j] = pack2bf(f[2*j], f[2*j+1]);
            #pragma unroll
            for (int t = 0; t < 3; ++t)
                acc[nt][t] = __builtin_amdgcn_mfma_f32_16x16x32_bf16(
                    afrag[t][kh], bf.v, acc[nt][t], 0, 0, 0);
        }
    }

    // --- theta: straight from C-regs (rows 0..7 of m-tile 0 = lanes l4<2)
    #pragma unroll
    for (int nt = 0; nt < 4; ++nt) {
        if (l4 < 2) {
            const int n = y * 64 + nt * 16 + l15;
            const unsigned lo = pack2bf(acc[nt][0][0], acc[nt][0][1]);
            const unsigned hi = pack2bf(acc[nt][0][2], acc[nt][0][3]);
            *(uint2*)(thetaT + ((size_t)b * N_ + n) * 8 + l4 * 4) = make_uint2(lo, hi);
        }
    }

    // --- stage phi/g to LDS for pooling
    #pragma unroll
    for (int nt = 0; nt < 4; ++nt) {
        const int px = wid * 64 + nt * 16 + l15;
        if (l4 >= 2) {                        // phi: ch = (l4-2)*4 + r
            #pragma unroll
            for (int r = 0; r < 4; ++r)
                sPool[((l4 - 2) * 4 + r) * SPSTR + px] = acc[nt][0][r];
        }
        #pragma unroll
        for (int r = 0; r < 4; ++r) {
            sPool[(8  + l4 * 4 + r) * SPSTR + px] = acc[nt][1][r];
            sPool[(24 + l4 * 4 + r) * SPSTR + px] = acc[nt][2][r];
        }
    }
    __syncthreads();

    // --- 2x2 maxpool + store: 40 ch x 64 pooled px per block
    {
        const int pm  = tid & 63, grp = tid >> 6;
        const int pr  = pm >> 5, pc = pm & 31;
        const int p00 = pr * 128 + pc * 2;
        const int mg  = ((y0 >> 1) + pr) * 32 + pc;
        #pragma unroll
        for (int i = 0; i < 10; ++i) {
            const int ch = grp * 10 + i;
            const float* sp = sPool + ch * SPSTR;
            const float v = fmaxf(fmaxf(sp[p00], sp[p00 + 1]),
                                  fmaxf(sp[p00 + 64], sp[p00 + 65]));
            if (ch < 8) phiT[((size_t)b * M_ + mg) * 8 + ch] = f2bf(v);
            else        gcm[((size_t)(b * 32 + ch - 8)) * M_ + mg] = f2bf(v);
        }
    }
}

// ---------------------------------------------------------------------------
// Kernel 2: MFMA flash attention + fused output conv + residual.
// (unchanged from round 2/3 — passed with absmax 0.0156)
// ---------------------------------------------------------------------------
#define GPAD   264   // sgT row stride (shorts): 256 + 8 -> 2-way banks (free)
#define PROW   40    // sP row stride (shorts): 80 B, 16B-aligned

__global__ __launch_bounds__(256) void attn_k(
    const float* __restrict__ x,
    const unsigned short* __restrict__ thetaT,
    const unsigned short* __restrict__ phiT,
    const unsigned short* __restrict__ gcm,
    const float* __restrict__ Wo, const float* __restrict__ bo,
    const float* __restrict__ gammap,
    float* __restrict__ out)
{
    __shared__ unsigned short sphi[2][128][8];   // 4 KB  even/odd key split
    __shared__ unsigned short sgT[32][GPAD];     // 16.9 KB [c][m]
    __shared__ unsigned short sP[4][32][PROW];   // 10.25 KB per-wave P slabs
    __shared__ float sO[32][132];                // 16.9 KB [c][q] epilogue

    const int tid  = threadIdx.x;
    const int lane = tid & 63;
    const int wid  = tid >> 6;
    const int l15  = lane & 15;
    const int l4   = lane >> 4;

    const int b  = blockIdx.x >> 5;
    const int q0 = (blockIdx.x & 31) << 7;   // 128 queries per block
    const int qw = q0 + wid * 32;            // this wave's first query

    // theta A-fragments (K=8 real, rest zero): lanes 16..63 are zero
    v8s aT[2];
    {
        v8s z = {};
        aT[0] = z; aT[1] = z;
        if (l4 == 0) {
            aT[0] = *(const v8s*)(thetaT + ((size_t)b * N_ + qw +      l15) * 8);
            aT[1] = *(const v8s*)(thetaT + ((size_t)b * N_ + qw + 16 + l15) * 8);
        }
    }

    v4f accO[2][2];
    #pragma unroll
    for (int qs = 0; qs < 2; ++qs)
        #pragma unroll
        for (int ct = 0; ct < 2; ++ct) { v4f z = {}; accO[qs][ct] = z; }
    float lsum[2][4] = {{0.f,0.f,0.f,0.f},{0.f,0.f,0.f,0.f}};
    const v4f zf = {};

    for (int t = 0; t < 4; ++t) {            // 4 key tiles of 256
        __syncthreads();
        // stage phi tile, split even/odd keys
        {
            const uint4 v = *(const uint4*)(phiT + ((size_t)b * M_ + t * 256 + tid) * 8);
            *(uint4*)&sphi[tid & 1][tid >> 1][0] = v;
        }
        // stage g tile channel-major [c][m]
        {
            const int row = tid >> 3, ch = tid & 7;
            const uint4* src = (const uint4*)(gcm + ((size_t)(b * 32 + row)) * M_ + t * 256 + ch * 32);
            uint4* dst = (uint4*)&sgT[row][ch * 32];
            dst[0] = src[0]; dst[1] = src[1]; dst[2] = src[2]; dst[3] = src[3];
        }
        __syncthreads();

        for (int cc = 0; cc < 8; ++cc) {     // 32-key chunks
            // phi B-frags: subtile kt covers keys {cc*32 + 2n + kt}
            v8s bph0, bph1;
            { v8s z = {}; bph0 = z; bph1 = z; }
            if (l4 == 0) {
                bph0 = *(const v8s*)&sphi[0][cc * 16 + l15][0];
                bph1 = *(const v8s*)&sphi[1][cc * 16 + l15][0];
            }
            // S tiles + exp + pack into per-wave sP slab (natural key order)
            #pragma unroll
            for (int qs = 0; qs < 2; ++qs) {
                v4f s0 = __builtin_amdgcn_mfma_f32_16x16x32_bf16(aT[qs], bph0, zf, 0, 0, 0);
                v4f s1 = __builtin_amdgcn_mfma_f32_16x16x32_bf16(aT[qs], bph1, zf, 0, 0, 0);
                #pragma unroll
                for (int r = 0; r < 4; ++r) {
                    float e0 = __expf(s0[r]);   // key cc*32 + 2*l15
                    float e1 = __expf(s1[r]);   // key cc*32 + 2*l15 + 1
                    lsum[qs][r] += e0 + e1;
                    *(unsigned*)&sP[wid][qs * 16 + l4 * 4 + r][2 * l15] = pack2bf(e0, e1);
                }
            }
            // G B-frags (shared by both q-subtiles)
            v8s bg0 = *(const v8s*)&sgT[l15     ][cc * 32 + l4 * 8];
            v8s bg1 = *(const v8s*)&sgT[16 + l15][cc * 32 + l4 * 8];
            // P A-frags (round-trip) + O MFMAs
            #pragma unroll
            for (int qs = 0; qs < 2; ++qs) {
                v8s ap = *(const v8s*)&sP[wid][qs * 16 + l15][l4 * 8];
                accO[qs][0] = __builtin_amdgcn_mfma_f32_16x16x32_bf16(ap, bg0, accO[qs][0], 0, 0, 0);
                accO[qs][1] = __builtin_amdgcn_mfma_f32_16x16x32_bf16(ap, bg1, accO[qs][1], 0, 0, 0);
            }
        }
    }

    // softmax denominators: reduce across the 16 key-columns (lane&15 groups)
    float rl[2][4];
    #pragma unroll
    for (int qs = 0; qs < 2; ++qs)
        #pragma unroll
        for (int r = 0; r < 4; ++r) {
            float v = lsum[qs][r];
            v += __shfl_xor(v, 1);
            v += __shfl_xor(v, 2);
            v += __shfl_xor(v, 4);
            v += __shfl_xor(v, 8);
            rl[qs][r] = 1.0f / v;
        }

    // write normalized O to LDS [c][q]
    #pragma unroll
    for (int qs = 0; qs < 2; ++qs)
        #pragma unroll
        for (int ct = 0; ct < 2; ++ct)
            #pragma unroll
            for (int r = 0; r < 4; ++r)
                sO[ct * 16 + l15][wid * 32 + qs * 16 + l4 * 4 + r] =
                    accO[qs][ct][r] * rl[qs][r];
    __syncthreads();

    // epilogue: out = gamma*(Wo . O + bo) + x.  Wave-uniform oc set ->
    // Wo/bo via scalar loads; O column from LDS (conflict-free).
    {
        const int qq   = tid & 127;
        const int half = tid >> 7;          // 0: oc 0..31, 1: oc 32..63
        const int n    = q0 + qq;
        float col[32];
        #pragma unroll
        for (int c = 0; c < 32; ++c) col[c] = sO[c][qq];
        const float gamma = *gammap;
        const float* xb = x   + ((size_t)(b * 64 + half * 32)) * N_ + n;
        float*       ob = out + ((size_t)(b * 64 + half * 32)) * N_ + n;
        #pragma unroll
        for (int j = 0; j < 32; ++j) {
            const int oc = half * 32 + j;
            const float* w = Wo + oc * 32;   // uniform -> s_load
            float r = 0.f;
            #pragma unroll
            for (int c = 0; c < 32; ++c) r = fmaf(w[c], col[c], r);
            ob[(size_t)j * N_] = gamma * (r + bo[oc]) + xb[(size_t)j * N_];
        }
    }
}

// ---------------------------------------------------------------------------
extern "C" void kernel_launch(void* const* d_in, const int* in_sizes, int n_in,
                              void* d_out, int out_size, void* d_ws, size_t ws_size,
                              hipStream_t stream) {
    const float* x  = (const float*)d_in[0];
    const float* Wt = (const float*)d_in[1];
    const float* bt = (const float*)d_in[2];
    const float* Wp = (const float*)d_in[3];
    const float* bp = (const float*)d_in[4];
    const float* Wg = (const float*)d_in[5];
    const float* bg = (const float*)d_in[6];
    const float* Wo = (const float*)d_in[7];
    const float* bo = (const float*)d_in[8];
    const float* gm = (const float*)d_in[9];
    float* out = (float*)d_out;

    // workspace (bf16): thetaT [16][4096][8] | phiT [16][1024][8] | gcm [16][32][1024]
    unsigned short* thetaT = (unsigned short*)d_ws;
    unsigned short* phiT   = thetaT + (size_t)B_ * N_ * 8;
    unsigned short* gcm    = phiT   + (size_t)B_ * M_ * 8;

    hipLaunchKernelGGL(conv_pool_k, dim3(256), dim3(256), 0, stream,
                       x, Wt, bt, Wp, bp, Wg, bg, thetaT, phiT, gcm);
    hipLaunchKernelGGL(attn_k, dim3(512), dim3(256), 0, stream,
                       x, thetaT, phiT, gcm, Wo, bo, gm, out);
}